// Round 8
// baseline (308.344 us; speedup 1.0000x reference)
//
#include <hip/hip_runtime.h>
#include <hip/hip_bf16.h>
#include <math.h>

// Problem constants
#define BATCH 2
#define SEQ   2048
#define NEMB  2048
#define NHEAD 16
#define HD    128
#define QKV_N 2304         // (16+2)*128
#define BT    (BATCH*SEQ)  // 4096

typedef short bf16x8 __attribute__((ext_vector_type(8)));
typedef float f32x4  __attribute__((ext_vector_type(4)));

#define AS_GLOBAL __attribute__((address_space(1)))
#define AS_LDS    __attribute__((address_space(3)))

static __device__ __forceinline__ void load_lds16(const void* g, void* l) {
    __builtin_amdgcn_global_load_lds((const AS_GLOBAL void*)g, (AS_LDS void*)l, 16, 0, 0);
}

static __device__ __forceinline__ unsigned short f2bfu(float f) {
    __hip_bfloat16 h = __float2bfloat16(f);
    return *reinterpret_cast<unsigned short*>(&h);
}

static __device__ __forceinline__ float fexp2(float x) {
    return __builtin_amdgcn_exp2f(x);
}

// ---------------------------------------------------------------------------
// Elementwise fp32 -> bf16 cast, 8 elements/thread.
// ---------------------------------------------------------------------------
__global__ __launch_bounds__(256) void cast_bf16(const float* __restrict__ in,
                                                 __hip_bfloat16* __restrict__ out) {
    int i = blockIdx.x * 256 + threadIdx.x;
    float4 a = *(const float4*)(in + (size_t)i * 8);
    float4 b = *(const float4*)(in + (size_t)i * 8 + 4);
    union { unsigned short u[8]; uint4 v; } pk;
    pk.u[0] = f2bfu(a.x); pk.u[1] = f2bfu(a.y); pk.u[2] = f2bfu(a.z); pk.u[3] = f2bfu(a.w);
    pk.u[4] = f2bfu(b.x); pk.u[5] = f2bfu(b.y); pk.u[6] = f2bfu(b.z); pk.u[7] = f2bfu(b.w);
    *(uint4*)(out + (size_t)i * 8) = pk.v;
}

// ---------------------------------------------------------------------------
// Transpose + cast: W fp32 [2048][N] -> WT bf16 [N][2048]. Grid (N/64, 32).
// PERM: permute q/k head columns (slots 0..16) so rope pair (d, d+64) maps
// to permuted positions (g*32+m, g*32+16+m) — 16 apart, same lane in the
// MFMA epilogue. v slot (17) identity. Attention is invariant under a
// consistent d-permutation of q and k.
// ---------------------------------------------------------------------------
template <bool PERM>
__global__ __launch_bounds__(256) void trans_cast(const float* __restrict__ W, int N,
                                                  __hip_bfloat16* __restrict__ WT) {
    __shared__ float tile[64][68];
    int n0 = blockIdx.x * 64, k0 = blockIdx.y * 64;
    int tid = threadIdx.x;
#pragma unroll
    for (int i = 0; i < 4; ++i) {
        int idx = tid + i * 256;
        int r = idx >> 4, c4 = (idx & 15) << 2;
        int np = n0 + c4;          // permuted (output) column base
        int src;
        if constexpr (PERM) {
            int slot = np >> 7, p = np & 127;
            if (slot < 17) {
                int g = p >> 5, half = (p >> 4) & 1, m = p & 15;
                src = slot * 128 + half * 64 + g * 16 + m;
            } else {
                src = np;
            }
        } else {
            src = np;
        }
        *(float4*)&tile[r][c4] = *(const float4*)&W[(size_t)(k0 + r) * N + src];
    }
    __syncthreads();
#pragma unroll
    for (int i = 0; i < 4; ++i) {
        int idx = tid + i * 256;
        int n = idx >> 4, kk = (idx & 15) << 2;
        ushort4 o;
        o.x = f2bfu(tile[kk + 0][n]);
        o.y = f2bfu(tile[kk + 1][n]);
        o.z = f2bfu(tile[kk + 2][n]);
        o.w = f2bfu(tile[kk + 3][n]);
        *(ushort4*)&WT[(size_t)(n0 + n) * 2048 + k0 + kk] = o;
    }
}

// ---------------------------------------------------------------------------
// MFMA bf16 GEMM: C[M][N] = A[M][K] * Bt[N][K]^T. 128x128 tile, BK=64,
// 256 threads (4 waves 2x2), 16x16x32 MFMA, global_load_lds + XOR swizzle.
// ROPE: apply rotary embedding in the epilogue (permuted layout: pair =
// (acc[i][j], acc[i][j+1]) for even j; orig freq index d = g*16+l15 with
// g = (wn>>5)+(j>>1)). Applies to bn<17 (q heads + k); bn==17 (v) skipped.
// ---------------------------------------------------------------------------
template <typename CT, bool ROPE>
__global__ __launch_bounds__(256, 2) void gemm_mfma(const __hip_bfloat16* __restrict__ A, int lda,
                                                    const __hip_bfloat16* __restrict__ Bt, int ldb,
                                                    CT* __restrict__ C, int ldc, int K) {
    __shared__ __hip_bfloat16 As[128 * 64];
    __shared__ __hip_bfloat16 Bs[128 * 64];

    int bn = blockIdx.x, bm = blockIdx.y;
    int tid = threadIdx.x;
    int lane = tid & 63, w = tid >> 6;
    int l15 = lane & 15, lq = lane >> 4;
    int wm = (w >> 1) * 64, wn = (w & 1) * 64;

    const __hip_bfloat16* Ab = A + (size_t)(bm * 128) * lda;
    const __hip_bfloat16* Bb = Bt + (size_t)(bn * 128) * ldb;

    int srow[4], skc[4];
#pragma unroll
    for (int p = 0; p < 4; ++p) {
        int c = p * 256 + tid;
        srow[p] = c >> 3;
        skc[p] = (c & 7) ^ (srow[p] & 7);
    }

    f32x4 acc[4][4];
#pragma unroll
    for (int i = 0; i < 4; ++i)
#pragma unroll
        for (int j = 0; j < 4; ++j) acc[i][j] = (f32x4){0.f, 0.f, 0.f, 0.f};

    for (int k0 = 0; k0 < K; k0 += 64) {
        __syncthreads();
#pragma unroll
        for (int p = 0; p < 4; ++p) {
            int c = p * 256 + tid;
            load_lds16(Ab + (size_t)srow[p] * lda + k0 + skc[p] * 8, As + c * 8);
            load_lds16(Bb + (size_t)srow[p] * ldb + k0 + skc[p] * 8, Bs + c * 8);
        }
        __syncthreads();

#pragma unroll
        for (int kc = 0; kc < 2; ++kc) {
            bf16x8 af[4], bf[4];
#pragma unroll
            for (int t = 0; t < 4; ++t) {
                int ma = wm + t * 16 + l15;
                af[t] = *(const bf16x8*)&As[(ma * 8 + ((kc * 4 + lq) ^ (ma & 7))) * 8];
                int nb = wn + t * 16 + l15;
                bf[t] = *(const bf16x8*)&Bs[(nb * 8 + ((kc * 4 + lq) ^ (nb & 7))) * 8];
            }
#pragma unroll
            for (int i = 0; i < 4; ++i)
#pragma unroll
                for (int j = 0; j < 4; ++j)
                    acc[i][j] = __builtin_amdgcn_mfma_f32_16x16x32_bf16(af[i], bf[j], acc[i][j], 0, 0, 0);
        }
    }

    int row0 = bm * 128 + wm, col0 = bn * 128 + wn;

    if constexpr (ROPE) {
        if (bn < 17) {
            // freqs for the two even-j groups this lane touches
            float fr[2];
#pragma unroll
            for (int jh = 0; jh < 2; ++jh) {
                int g = (wn >> 5) + jh;
                float dlow = (float)(g * 16 + l15);
                fr[jh] = fexp2(-13.287712379549449f * (4.0f * dlow + 1.0f) * (1.0f / 128.0f)) *
                         0.15915494309189535f;   // revolutions
            }
#pragma unroll
            for (int i = 0; i < 4; ++i)
#pragma unroll
                for (int r = 0; r < 4; ++r) {
                    int row = row0 + i * 16 + lq * 4 + r;
                    float tpos = (float)(row & (SEQ - 1));
#pragma unroll
                    for (int jh = 0; jh < 2; ++jh) {
                        int j = jh * 2;
                        float rev = tpos * fr[jh];
                        float red = rev - floorf(rev);
                        float sn = __builtin_amdgcn_sinf(red);
                        float cs = __builtin_amdgcn_cosf(red);
                        float x1 = acc[i][j][r];
                        float x2 = acc[i][j + 1][r];
                        acc[i][j][r]     = x1 * cs - x2 * sn;
                        acc[i][j + 1][r] = x2 * cs + x1 * sn;
                    }
                }
        }
    }

#pragma unroll
    for (int i = 0; i < 4; ++i)
#pragma unroll
        for (int j = 0; j < 4; ++j)
#pragma unroll
            for (int r = 0; r < 4; ++r) {
                int row = row0 + i * 16 + lq * 4 + r;
                int col = col0 + j * 16 + l15;
                float v = acc[i][j][r];
                if constexpr (__is_same(CT, float)) {
                    C[(size_t)row * ldc + col] = v;
                } else {
                    C[(size_t)row * ldc + col] = __float2bfloat16(v);
                }
            }
}

// ---------------------------------------------------------------------------
// V transpose: qkv bf16 [b][t][2176+d] -> vT bf16 [b][d][t]. Grid (32, 2, 2).
// ---------------------------------------------------------------------------
__global__ __launch_bounds__(256) void transpose_v(const __hip_bfloat16* __restrict__ qkv,
                                                   __hip_bfloat16* __restrict__ vT) {
    __shared__ unsigned short tile[64][72];
    int tt = blockIdx.x, dd = blockIdx.y, b = blockIdx.z;
    int tid = threadIdx.x;
#pragma unroll
    for (int i = 0; i < 4; ++i) {
        int idx = tid + i * 256;
        int r = idx >> 4, c4 = (idx & 15) << 2;
        *(ushort4*)&tile[r][c4] = *(const ushort4*)&qkv[(size_t)(b * SEQ + tt * 64 + r) * QKV_N +
                                                        (NHEAD + 1) * HD + dd * 64 + c4];
    }
    __syncthreads();
#pragma unroll
    for (int i = 0; i < 4; ++i) {
        int idx = tid + i * 256;
        int dl = idx >> 4, t4 = (idx & 15) << 2;
        ushort4 o;
        o.x = tile[t4 + 0][dl];
        o.y = tile[t4 + 1][dl];
        o.z = tile[t4 + 2][dl];
        o.w = tile[t4 + 3][dl];
        *(ushort4*)&vT[(size_t)(b * HD + dd * 64 + dl) * SEQ + tt * 64 + t4] = o;
    }
}

// ---------------------------------------------------------------------------
// MFMA bf16 flash attention, S^T scheme + fixed-max softmax, KT=128 staging
// (two 64-row halves per barrier; halves the vmcnt(0)+barrier drains).
// q/k are d-permuted (consistent) — S invariant. O written over own q slot.
// ---------------------------------------------------------------------------
__global__ __launch_bounds__(256, 2) void attn_mfma(__hip_bfloat16* __restrict__ qkv,
                                                    const __hip_bfloat16* __restrict__ vT) {
    int qt = blockIdx.x;   // 0..15
    int h  = blockIdx.y;   // 0..15
    int b  = blockIdx.z;   // 0..1
    int tid  = threadIdx.x;
    int w    = tid >> 6;
    int lane = tid & 63;
    int l15  = lane & 15;
    int lq   = lane >> 4;
    int l7   = l15 & 7;

    __shared__ __hip_bfloat16 Ks[128 * 128];  // 32 KB, swizzled (row=k-time)
    __shared__ __hip_bfloat16 Vt[128 * 128];  // 32 KB, swizzled (row=d)
    __shared__ __hip_bfloat16 Ps[4][32 * 64]; // 16 KB, per-wave P, swizzled

    int qrow0 = b * SEQ + qt * 128 + w * 32;
    bf16x8 qf[2][4];
#pragma unroll
    for (int qb2 = 0; qb2 < 2; ++qb2)
#pragma unroll
        for (int kc = 0; kc < 4; ++kc)
            qf[qb2][kc] = *(const bf16x8*)&qkv[(size_t)(qrow0 + qb2 * 16 + l15) * QKV_N +
                                              h * HD + kc * 32 + lq * 8];

    f32x4 of[2][8];
#pragma unroll
    for (int qb2 = 0; qb2 < 2; ++qb2)
#pragma unroll
        for (int db = 0; db < 8; ++db) of[qb2][db] = (f32x4){0.f, 0.f, 0.f, 0.f};
    float l_st[2] = {0.f, 0.f};

    const size_t kbase = (size_t)b * SEQ * QKV_N + NHEAD * HD;  // k at col 2048
    const size_t vbase = (size_t)b * HD * SEQ;
    const float sl2e = 0.08838834764831845f * 1.4426950408889634f;  // scale*log2(e)
    const float MFIX = 16.0f;

    for (int kt = 0; kt < SEQ / 128; ++kt) {
        __syncthreads();
        // Stage K tile 128x128: 2048 chunks of 16B, 8/thread.
#pragma unroll
        for (int i = 0; i < 8; ++i) {
            int c = tid + i * 256;
            int r = c >> 4, sc = (c & 15) ^ (r & 15);
            load_lds16(&qkv[kbase + (size_t)(kt * 128 + r) * QKV_N + sc * 8], &Ks[c * 8]);
        }
        // Stage V^T tile 128x128: 2048 chunks, 8/thread.
#pragma unroll
        for (int i = 0; i < 8; ++i) {
            int c = tid + i * 256;
            int d = c >> 4, sc = (c & 15) ^ (d & 15);
            load_lds16(&vT[vbase + (size_t)d * SEQ + kt * 128 + sc * 8], &Vt[c * 8]);
        }
        __syncthreads();

#pragma unroll
        for (int half = 0; half < 2; ++half) {
            // --- S^T = K.Q^T (64 k-rows x 32 q-cols per wave) ---
            f32x4 sf[4][2];
#pragma unroll
            for (int kb = 0; kb < 4; ++kb) {
                int krow = half * 64 + kb * 16 + l15;   // krow&15 == l15
                bf16x8 kf[4];
#pragma unroll
                for (int kc = 0; kc < 4; ++kc)
                    kf[kc] = *(const bf16x8*)&Ks[(krow * 16 + ((kc * 4 + lq) ^ l15)) * 8];
#pragma unroll
                for (int qb2 = 0; qb2 < 2; ++qb2) {
                    f32x4 acc = (f32x4){0.f, 0.f, 0.f, 0.f};
#pragma unroll
                    for (int kc = 0; kc < 4; ++kc)
                        acc = __builtin_amdgcn_mfma_f32_16x16x32_bf16(kf[kc], qf[qb2][kc], acc, 0, 0, 0);
                    sf[kb][qb2] = acc;
                }
            }

            // --- fixed-max softmax: p = exp2(s*sl2e - 16) ---
#pragma unroll
            for (int qb2 = 0; qb2 < 2; ++qb2) {
                float sum = 0.f;
                int qr = qb2 * 16 + l15;
#pragma unroll
                for (int kb = 0; kb < 4; ++kb) {
                    float p0 = fexp2(fmaf(sf[kb][qb2][0], sl2e, -MFIX));
                    float p1 = fexp2(fmaf(sf[kb][qb2][1], sl2e, -MFIX));
                    float p2 = fexp2(fmaf(sf[kb][qb2][2], sl2e, -MFIX));
                    float p3 = fexp2(fmaf(sf[kb][qb2][3], sl2e, -MFIX));
                    sum += (p0 + p1) + (p2 + p3);
                    ushort4 pk;
                    pk.x = f2bfu(p0); pk.y = f2bfu(p1); pk.z = f2bfu(p2); pk.w = f2bfu(p3);
                    int cc = (kb * 2 + (lq >> 1)) ^ l7;
                    *(ushort4*)&Ps[w][(qr * 8 + cc) * 8 + (lq & 1) * 4] = pk;
                }
                l_st[qb2] += sum;
            }

            // --- O += P.V^T (wave-private Ps) ---
#pragma unroll
            for (int kc2 = 0; kc2 < 2; ++kc2) {
                bf16x8 pa[2];
#pragma unroll
                for (int qb2 = 0; qb2 < 2; ++qb2)
                    pa[qb2] = *(const bf16x8*)&Ps[w][((qb2 * 16 + l15) * 8 +
                                                     ((kc2 * 4 + lq) ^ l7)) * 8];
#pragma unroll
                for (int db = 0; db < 8; ++db) {
                    int drow = db * 16 + l15;   // drow&15 == l15
                    bf16x8 vb = *(const bf16x8*)&Vt[(drow * 16 +
                                                    ((half * 8 + kc2 * 4 + lq) ^ l15)) * 8];
#pragma unroll
                    for (int qb2 = 0; qb2 < 2; ++qb2)
                        of[qb2][db] = __builtin_amdgcn_mfma_f32_16x16x32_bf16(pa[qb2], vb, of[qb2][db], 0, 0, 0);
                }
            }
        }
    }

    // --- reduce l across quads, normalize, write over own q slot ---
    float i_t[2][4];
#pragma unroll
    for (int qb2 = 0; qb2 < 2; ++qb2) {
        float l = l_st[qb2];
        l += __shfl_xor(l, 16, 64);
        l += __shfl_xor(l, 32, 64);
        float inv = 1.0f / l;
#pragma unroll
        for (int r = 0; r < 4; ++r) i_t[qb2][r] = __shfl(inv, lq * 4 + r, 64);
    }
#pragma unroll
    for (int qb2 = 0; qb2 < 2; ++qb2)
#pragma unroll
        for (int db = 0; db < 8; ++db)
#pragma unroll
            for (int r = 0; r < 4; ++r) {
                float v = of[qb2][db][r] * i_t[qb2][r];
                qkv[(size_t)(qrow0 + qb2 * 16 + lq * 4 + r) * QKV_N + h * HD + db * 16 + l15] =
                    __float2bfloat16(v);
            }
}

// ---------------------------------------------------------------------------
// ws: qkvb bf16 [4096][2304] @0 (18.87 MB); wT bf16 [<=2304][2048] @18.87M
// (9.44 MB, shared by w_attn then w_out); vT @28.3M (1.05 MB). Total 29.36 MB.
// xb bf16 [4096][2048] lives in d_out (16.78 MB), consumed before GEMM2.
// ---------------------------------------------------------------------------
extern "C" void kernel_launch(void* const* d_in, const int* in_sizes, int n_in,
                              void* d_out, int out_size, void* d_ws, size_t ws_size,
                              hipStream_t stream) {
    const float* x      = (const float*)d_in[0];
    const float* w_attn = (const float*)d_in[1];
    const float* w_out  = (const float*)d_in[2];
    float* out = (float*)d_out;

    char* ws = (char*)d_ws;
    __hip_bfloat16* qkvb = (__hip_bfloat16*)ws;                    // 18,874,368 B
    __hip_bfloat16* wT   = (__hip_bfloat16*)(ws + 18874368);       //  9,437,184 B
    __hip_bfloat16* vT   = (__hip_bfloat16*)(ws + 28311552);       //  1,048,576 B
    __hip_bfloat16* xb   = (__hip_bfloat16*)d_out;                 // 16,777,216 B temp

    // 1. casts / transposes for GEMM1 (w_attn columns rope-permuted)
    cast_bf16<<<(BT * NEMB / 8) / 256, 256, 0, stream>>>(x, xb);
    trans_cast<true><<<dim3(QKV_N / 64, NEMB / 64), 256, 0, stream>>>(w_attn, QKV_N, wT);

    // 2. qkv = x @ w_attn  (MFMA, bf16 out, fused RoPE on q heads + k)
    gemm_mfma<__hip_bfloat16, true><<<dim3(QKV_N / 128, BT / 128), 256, 0, stream>>>(
        xb, NEMB, wT, NEMB, qkvb, QKV_N, NEMB);

    // 3. V transpose
    transpose_v<<<dim3(SEQ / 64, HD / 64, BATCH), 256, 0, stream>>>(qkvb, vT);

    // 4. flash attention (overwrites q slots in qkvb)
    attn_mfma<<<dim3(SEQ / 128, NHEAD, BATCH), 256, 0, stream>>>(qkvb, vT);

    // 5. transpose w_out (identity), then out = attn @ w_out (fp32 out)
    trans_cast<false><<<dim3(NEMB / 64, NEMB / 64), 256, 0, stream>>>(w_out, NEMB, wT);
    gemm_mfma<float, false><<<dim3(NEMB / 128, BT / 128), 256, 0, stream>>>(
        qkvb, QKV_N, wT, NEMB, out, NEMB, NEMB);
}